// Round 9
// baseline (189.556 us; speedup 1.0000x reference)
//
#include <hip/hip_runtime.h>
#include <hip/hip_bf16.h>

#define B_ROWS  2048
#define T_DIM   8
#define IN_DIM  1024
#define OUT_DIM 4096
#define NE      12

#define M_TILE 256
#define N_TILE 64
#define K_STEP 32
#define NSTEP  (IN_DIM / K_STEP)

typedef __attribute__((ext_vector_type(8))) short short8;
typedef __attribute__((ext_vector_type(4))) float f32x4;

union S8U { short8 s; unsigned u[4]; };

// two floats -> packed bf16x2 (v_cvt_pk_bf16_f32, RNE)
__device__ __forceinline__ unsigned cvt2(float a, float b) {
  __hip_bfloat162 h = __float22bfloat162_rn(make_float2(a, b));
  union { __hip_bfloat162 h; unsigned u; } c; c.h = h;
  return c.u;
}

// barrier WITHOUT vmcnt drain: ds-write visibility only (T4 pattern)
__device__ __forceinline__ void barrier_lgkm() {
  asm volatile("s_waitcnt lgkmcnt(0)" ::: "memory");
  __builtin_amdgcn_s_barrier();
}

// ---------------- kernel P: transpose Wg[4096][12] -> WgT[12][4096] --------
__global__ __launch_bounds__(256) void wg_transpose(
    const float* __restrict__ Wg, float* __restrict__ wgt)
{
  const int c = blockIdx.x * 256 + threadIdx.x;   // 0..4095
  #pragma unroll
  for (int e = 0; e < NE; ++e)
    wgt[(size_t)e * OUT_DIM + c] = Wg[(size_t)c * NE + e];
}

// ---------------- kernel A: gate (round-5 passing version, unchanged) ------
__global__ __launch_bounds__(256) void gate_kernel(
    const float* __restrict__ t, const float* __restrict__ wgt,
    const float* __restrict__ bg, int* __restrict__ counts,
    int* __restrict__ rowlist)
{
  const int b   = blockIdx.x;
  const int tid = threadIdx.x;
  const float* tb = t + (size_t)b * T_DIM * OUT_DIM;

  float4 m[4];
  #pragma unroll
  for (int it = 0; it < 4; ++it) {
    const int c = (tid + it * 256) * 4;
    float4 s = make_float4(0.f, 0.f, 0.f, 0.f);
    #pragma unroll
    for (int tt = 0; tt < T_DIM; ++tt) {
      const float4 v = *(const float4*)(tb + (size_t)tt * OUT_DIM + c);
      s.x += v.x; s.y += v.y; s.z += v.z; s.w += v.w;
    }
    m[it] = make_float4(s.x * 0.125f, s.y * 0.125f, s.z * 0.125f, s.w * 0.125f);
  }

  float part[NE];
  #pragma unroll
  for (int e = 0; e < NE; ++e) {
    float acc = 0.f;
    #pragma unroll
    for (int it = 0; it < 4; ++it) {
      const int c = (tid + it * 256) * 4;
      const float4 w = *(const float4*)(wgt + (size_t)e * OUT_DIM + c);
      acc += m[it].x * w.x; acc += m[it].y * w.y;
      acc += m[it].z * w.z; acc += m[it].w * w.w;
    }
    part[e] = acc;
  }

  double d[NE];
  #pragma unroll
  for (int e = 0; e < NE; ++e) d[e] = (double)part[e];
  #pragma unroll
  for (int off = 32; off > 0; off >>= 1) {
    #pragma unroll
    for (int e = 0; e < NE; ++e) d[e] += __shfl_down(d[e], off, 64);
  }

  __shared__ double wsred[4][NE];
  const int lane = tid & 63, wave = tid >> 6;
  if (lane == 0) {
    #pragma unroll
    for (int e = 0; e < NE; ++e) wsred[wave][e] = d[e];
  }
  __syncthreads();

  if (tid == 0) {
    double best = -1e300; int bi = 0;
    #pragma unroll
    for (int e = 0; e < NE; ++e) {
      const double v = wsred[0][e] + wsred[1][e] + wsred[2][e] + wsred[3][e] + (double)bg[e];
      if (v > best) { best = v; bi = e; }
    }
    const int pos = atomicAdd(&counts[bi], 1);
    rowlist[bi * B_ROWS + pos] = b;
  }
}

// fallback gate (scalar Wg) if workspace can't hold WgT
__global__ __launch_bounds__(256) void gate_fallback(
    const float* __restrict__ t, const float* __restrict__ Wg,
    const float* __restrict__ bg, int* __restrict__ counts,
    int* __restrict__ rowlist)
{
  const int b   = blockIdx.x;
  const int tid = threadIdx.x;
  const float* tb = t + (size_t)b * T_DIM * OUT_DIM;

  float part[NE];
  #pragma unroll
  for (int e = 0; e < NE; ++e) part[e] = 0.f;
  #pragma unroll
  for (int it = 0; it < 4; ++it) {
    const int c = (tid + it * 256) * 4;
    float4 s = make_float4(0.f, 0.f, 0.f, 0.f);
    #pragma unroll
    for (int tt = 0; tt < T_DIM; ++tt) {
      const float4 v = *(const float4*)(tb + (size_t)tt * OUT_DIM + c);
      s.x += v.x; s.y += v.y; s.z += v.z; s.w += v.w;
    }
    const float mm[4] = { s.x * 0.125f, s.y * 0.125f, s.z * 0.125f, s.w * 0.125f };
    #pragma unroll
    for (int j = 0; j < 4; ++j) {
      const float* wg = Wg + (size_t)(c + j) * NE;
      #pragma unroll
      for (int e = 0; e < NE; ++e) part[e] += mm[j] * wg[e];
    }
  }
  double d[NE];
  #pragma unroll
  for (int e = 0; e < NE; ++e) d[e] = (double)part[e];
  #pragma unroll
  for (int off = 32; off > 0; off >>= 1) {
    #pragma unroll
    for (int e = 0; e < NE; ++e) d[e] += __shfl_down(d[e], off, 64);
  }
  __shared__ double wsred[4][NE];
  const int lane = tid & 63, wave = tid >> 6;
  if (lane == 0) {
    #pragma unroll
    for (int e = 0; e < NE; ++e) wsred[wave][e] = d[e];
  }
  __syncthreads();
  if (tid == 0) {
    double best = -1e300; int bi = 0;
    #pragma unroll
    for (int e = 0; e < NE; ++e) {
      const double v = wsred[0][e] + wsred[1][e] + wsred[2][e] + wsred[3][e] + (double)bg[e];
      if (v > best) { best = v; bi = e; }
    }
    const int pos = atomicAdd(&counts[bi], 1);
    rowlist[bi * B_ROWS + pos] = b;
  }
}

// ---------------- kernel B: grouped bf16-MFMA GEMM, 256x64 tiles ------------
// W-once: M_TILE=256 covers every expert's full row set (cnt~170).
// Concurrency: 12 experts x 64 col-blocks = 768 blocks (3 waves/SIMD).
// XCD clustering: work = (bid%8)*96 + bid/8 -> XCD k owns contiguous works
// [96k,96k+96) = 1.5 experts, so each expert's gathered-x slice (~680 KB)
// stays L2-resident across its 64 col-blocks. L3-path bytes ~224 MB.
// Per-thread pipeline identical to proven round-5 kernel.
__global__ __launch_bounds__(256) void expert_gemm(
    const float* __restrict__ x, const float* __restrict__ W,
    const float* __restrict__ bias, const int* __restrict__ counts,
    const int* __restrict__ rowlist, float* __restrict__ out)
{
  const int bid  = blockIdx.x;
  const int work = (bid & 7) * 96 + (bid >> 3);   // bijective [0,768)
  const int e    = work >> 6;                     // 64 col-blocks per expert
  const int c0   = (work & 63) * N_TILE;
  const int cnt  = counts[e];
  const int row0 = blockIdx.y * M_TILE;
  if (row0 >= cnt) return;                        // y>0 only if cnt>256
  const int* rl  = rowlist + e * B_ROWS;

  __shared__ short8 xa[2][1024];   // A: 2 x 16 KiB (256 rows x 32 k)
  __shared__ short8 wb[2][256];    // B: 2 x  4 KiB ( 64 cols x 32 k)

  const int tid  = threadIdx.x;
  const int lane = tid & 63;
  const int wave = tid >> 6;

  // staging geometry (fragment-order slots; all LDS ops wave-contiguous b128)
  const int sg  = (tid >> 4) & 3;   // k-subgroup (k = 8*sg + j)
  const int slr = tid & 15;         // lr / lc
  const int smb = tid >> 6;         // base frag-block

  // A: slots {tid, tid+256, tid+512, tid+768} -> rows 16*smb + 64*i + slr
  const float* xp[4];
  #pragma unroll
  for (int i = 0; i < 4; ++i) {
    const int g = row0 + smb * 16 + 64 * i + slr;
    xp[i] = x + (size_t)rl[g < cnt ? g : cnt - 1] * IN_DIM + sg * 8;
  }
  // B: slot tid -> col c0 + 16*smb + slr
  const float* wp = W + (size_t)e * IN_DIM * OUT_DIM
                      + (size_t)(sg * 8) * OUT_DIM + c0 + smb * 16 + slr;

  // MFMA geometry: wave w -> rows [64w, 64w+64) x all 64 cols
  const int wm    = wave * 64;
  const int abase = wave * 256;

  f32x4 acc[4][4];
  #pragma unroll
  for (int m = 0; m < 4; ++m)
    #pragma unroll
    for (int n = 0; n < 4; ++n)
      #pragma unroll
      for (int q = 0; q < 4; ++q) acc[m][n][q] = 0.f;

  // staging registers (static names; no runtime indexing)
  float4 axl0, axh0, axl1, axh1, axl2, axh2, axl3, axh3;
  float w0[8];

#define ISSUE_LOADS(K)                                                  \
  {                                                                     \
    axl0 = *(const float4*)(xp[0] + (K)); axh0 = *(const float4*)(xp[0] + (K) + 4); \
    axl1 = *(const float4*)(xp[1] + (K)); axh1 = *(const float4*)(xp[1] + (K) + 4); \
    axl2 = *(const float4*)(xp[2] + (K)); axh2 = *(const float4*)(xp[2] + (K) + 4); \
    axl3 = *(const float4*)(xp[3] + (K)); axh3 = *(const float4*)(xp[3] + (K) + 4); \
    const float* p = wp + (size_t)(K) * OUT_DIM;                        \
    _Pragma("unroll")                                                   \
    for (int j = 0; j < 8; ++j) w0[j] = p[(size_t)j * OUT_DIM];         \
  }

  ISSUE_LOADS(0);

  for (int it = 0; it < NSTEP; ++it) {
    S8U av0, av1, av2, av3, bv0;
    av0.u[0] = cvt2(axl0.x, axl0.y); av0.u[1] = cvt2(axl0.z, axl0.w);
    av0.u[2] = cvt2(axh0.x, axh0.y); av0.u[3] = cvt2(axh0.z, axh0.w);
    av1.u[0] = cvt2(axl1.x, axl1.y); av1.u[1] = cvt2(axl1.z, axl1.w);
    av1.u[2] = cvt2(axh1.x, axh1.y); av1.u[3] = cvt2(axh1.z, axh1.w);
    av2.u[0] = cvt2(axl2.x, axl2.y); av2.u[1] = cvt2(axl2.z, axl2.w);
    av2.u[2] = cvt2(axh2.x, axh2.y); av2.u[3] = cvt2(axh2.z, axh2.w);
    av3.u[0] = cvt2(axl3.x, axl3.y); av3.u[1] = cvt2(axl3.z, axl3.w);
    av3.u[2] = cvt2(axh3.x, axh3.y); av3.u[3] = cvt2(axh3.z, axh3.w);
    #pragma unroll
    for (int q = 0; q < 4; ++q)
      bv0.u[q] = cvt2(w0[2 * q], w0[2 * q + 1]);

    if (it + 1 < NSTEP) ISSUE_LOADS((it + 1) * K_STEP);

    const int buf = it & 1;
    xa[buf][tid]       = av0.s;
    xa[buf][tid + 256] = av1.s;
    xa[buf][tid + 512] = av2.s;
    xa[buf][tid + 768] = av3.s;
    wb[buf][tid < 256 ? tid : tid] = bv0.s;   // slot tid (all 256 threads)
    barrier_lgkm();   // ds-writes visible; in-flight global loads survive

    short8 af[4], bf[4];
    #pragma unroll
    for (int m = 0; m < 4; ++m) af[m] = xa[buf][abase + m * 64 + lane];
    #pragma unroll
    for (int n = 0; n < 4; ++n) bf[n] = wb[buf][n * 64 + lane];
    #pragma unroll
    for (int m = 0; m < 4; ++m)
      #pragma unroll
      for (int n = 0; n < 4; ++n)
        acc[m][n] = __builtin_amdgcn_mfma_f32_16x16x32_bf16(af[m], bf[n], acc[m][n], 0, 0, 0);
  }
#undef ISSUE_LOADS

  // epilogue: C/D layout col = lane&15, row = (lane>>4)*4 + r
  const int lr = lane & 15;
  const int lq = (lane >> 4) * 4;
  float bcol[4];
  #pragma unroll
  for (int n = 0; n < 4; ++n)
    bcol[n] = bias[e * OUT_DIM + c0 + n * 16 + lr];

  #pragma unroll
  for (int m = 0; m < 4; ++m) {
    #pragma unroll
    for (int r = 0; r < 4; ++r) {
      const int gidx = row0 + wm + m * 16 + lq + r;
      if (gidx >= cnt) continue;
      const int grow = rl[gidx];
      float* orow = out + (size_t)grow * OUT_DIM;
      #pragma unroll
      for (int n = 0; n < 4; ++n) {
        const int col = c0 + n * 16 + lr;
        orow[col] = acc[m][n][r] + bcol[n];
      }
    }
  }
}

extern "C" void kernel_launch(void* const* d_in, const int* in_sizes, int n_in,
                              void* d_out, int out_size, void* d_ws, size_t ws_size,
                              hipStream_t stream) {
  (void)in_sizes; (void)n_in; (void)out_size;
  const float* x  = (const float*)d_in[0];
  const float* t  = (const float*)d_in[1];
  const float* W  = (const float*)d_in[2];
  const float* bb = (const float*)d_in[3];
  const float* Wg = (const float*)d_in[4];
  const float* bg = (const float*)d_in[5];
  float* out = (float*)d_out;

  int*   counts  = (int*)d_ws;                                  // 16 ints
  int*   rowlist = (int*)d_ws + 16;                             // 12*2048 ints
  float* wgt     = (float*)((char*)d_ws + 64 + NE * B_ROWS * 4);// 12*4096 f32
  const size_t need = 64 + (size_t)NE * B_ROWS * 4 + (size_t)NE * OUT_DIM * 4;

  hipMemsetAsync(counts, 0, 16 * sizeof(int), stream);
  if (ws_size >= need) {
    wg_transpose<<<OUT_DIM / 256, 256, 0, stream>>>(Wg, wgt);
    gate_kernel<<<B_ROWS, 256, 0, stream>>>(t, wgt, bg, counts, rowlist);
  } else {
    gate_fallback<<<B_ROWS, 256, 0, stream>>>(t, Wg, bg, counts, rowlist);
  }

  dim3 grid(NE * (OUT_DIM / N_TILE), B_ROWS / M_TILE, 1);
  expert_gemm<<<grid, 256, 0, stream>>>(x, W, bb, counts, rowlist, out);
}

// Round 10
// 183.323 us; speedup vs baseline: 1.0340x; 1.0340x over previous
//
#include <hip/hip_runtime.h>
#include <hip/hip_bf16.h>

#define B_ROWS  2048
#define T_DIM   8
#define IN_DIM  1024
#define OUT_DIM 4096
#define NE      12

#define M_TILE 128
#define N_TILE 64
#define K_STEP 32
#define NSTEP  (IN_DIM / K_STEP)
#define NWORK  (NE * (OUT_DIM / N_TILE) * 2)   // 1536: e x col x row-tile

typedef __attribute__((ext_vector_type(8))) short short8;
typedef __attribute__((ext_vector_type(4))) float f32x4;

union S8U { short8 s; unsigned u[4]; };

// two floats -> packed bf16x2 (v_cvt_pk_bf16_f32, RNE)
__device__ __forceinline__ unsigned cvt2(float a, float b) {
  __hip_bfloat162 h = __float22bfloat162_rn(make_float2(a, b));
  union { __hip_bfloat162 h; unsigned u; } c; c.h = h;
  return c.u;
}

// barrier WITHOUT vmcnt drain: ds-write visibility only (T4 pattern)
__device__ __forceinline__ void barrier_lgkm() {
  asm volatile("s_waitcnt lgkmcnt(0)" ::: "memory");
  __builtin_amdgcn_s_barrier();
}

// ---------------- kernel P: transpose Wg[4096][12] -> WgT[12][4096] --------
__global__ __launch_bounds__(256) void wg_transpose(
    const float* __restrict__ Wg, float* __restrict__ wgt)
{
  const int c = blockIdx.x * 256 + threadIdx.x;   // 0..4095
  #pragma unroll
  for (int e = 0; e < NE; ++e)
    wgt[(size_t)e * OUT_DIM + c] = Wg[(size_t)c * NE + e];
}

// ---------------- kernel A: gate (round-5 passing version, unchanged) ------
__global__ __launch_bounds__(256) void gate_kernel(
    const float* __restrict__ t, const float* __restrict__ wgt,
    const float* __restrict__ bg, int* __restrict__ counts,
    int* __restrict__ rowlist)
{
  const int b   = blockIdx.x;
  const int tid = threadIdx.x;
  const float* tb = t + (size_t)b * T_DIM * OUT_DIM;

  float4 m[4];
  #pragma unroll
  for (int it = 0; it < 4; ++it) {
    const int c = (tid + it * 256) * 4;
    float4 s = make_float4(0.f, 0.f, 0.f, 0.f);
    #pragma unroll
    for (int tt = 0; tt < T_DIM; ++tt) {
      const float4 v = *(const float4*)(tb + (size_t)tt * OUT_DIM + c);
      s.x += v.x; s.y += v.y; s.z += v.z; s.w += v.w;
    }
    m[it] = make_float4(s.x * 0.125f, s.y * 0.125f, s.z * 0.125f, s.w * 0.125f);
  }

  float part[NE];
  #pragma unroll
  for (int e = 0; e < NE; ++e) {
    float acc = 0.f;
    #pragma unroll
    for (int it = 0; it < 4; ++it) {
      const int c = (tid + it * 256) * 4;
      const float4 w = *(const float4*)(wgt + (size_t)e * OUT_DIM + c);
      acc += m[it].x * w.x; acc += m[it].y * w.y;
      acc += m[it].z * w.z; acc += m[it].w * w.w;
    }
    part[e] = acc;
  }

  double d[NE];
  #pragma unroll
  for (int e = 0; e < NE; ++e) d[e] = (double)part[e];
  #pragma unroll
  for (int off = 32; off > 0; off >>= 1) {
    #pragma unroll
    for (int e = 0; e < NE; ++e) d[e] += __shfl_down(d[e], off, 64);
  }

  __shared__ double wsred[4][NE];
  const int lane = tid & 63, wave = tid >> 6;
  if (lane == 0) {
    #pragma unroll
    for (int e = 0; e < NE; ++e) wsred[wave][e] = d[e];
  }
  __syncthreads();

  if (tid == 0) {
    double best = -1e300; int bi = 0;
    #pragma unroll
    for (int e = 0; e < NE; ++e) {
      const double v = wsred[0][e] + wsred[1][e] + wsred[2][e] + wsred[3][e] + (double)bg[e];
      if (v > best) { best = v; bi = e; }
    }
    const int pos = atomicAdd(&counts[bi], 1);
    rowlist[bi * B_ROWS + pos] = b;
  }
}

// fallback gate (scalar Wg) if workspace can't hold WgT
__global__ __launch_bounds__(256) void gate_fallback(
    const float* __restrict__ t, const float* __restrict__ Wg,
    const float* __restrict__ bg, int* __restrict__ counts,
    int* __restrict__ rowlist)
{
  const int b   = blockIdx.x;
  const int tid = threadIdx.x;
  const float* tb = t + (size_t)b * T_DIM * OUT_DIM;

  float part[NE];
  #pragma unroll
  for (int e = 0; e < NE; ++e) part[e] = 0.f;
  #pragma unroll
  for (int it = 0; it < 4; ++it) {
    const int c = (tid + it * 256) * 4;
    float4 s = make_float4(0.f, 0.f, 0.f, 0.f);
    #pragma unroll
    for (int tt = 0; tt < T_DIM; ++tt) {
      const float4 v = *(const float4*)(tb + (size_t)tt * OUT_DIM + c);
      s.x += v.x; s.y += v.y; s.z += v.z; s.w += v.w;
    }
    const float mm[4] = { s.x * 0.125f, s.y * 0.125f, s.z * 0.125f, s.w * 0.125f };
    #pragma unroll
    for (int j = 0; j < 4; ++j) {
      const float* wg = Wg + (size_t)(c + j) * NE;
      #pragma unroll
      for (int e = 0; e < NE; ++e) part[e] += mm[j] * wg[e];
    }
  }
  double d[NE];
  #pragma unroll
  for (int e = 0; e < NE; ++e) d[e] = (double)part[e];
  #pragma unroll
  for (int off = 32; off > 0; off >>= 1) {
    #pragma unroll
    for (int e = 0; e < NE; ++e) d[e] += __shfl_down(d[e], off, 64);
  }
  __shared__ double wsred[4][NE];
  const int lane = tid & 63, wave = tid >> 6;
  if (lane == 0) {
    #pragma unroll
    for (int e = 0; e < NE; ++e) wsred[wave][e] = d[e];
  }
  __syncthreads();
  if (tid == 0) {
    double best = -1e300; int bi = 0;
    #pragma unroll
    for (int e = 0; e < NE; ++e) {
      const double v = wsred[0][e] + wsred[1][e] + wsred[2][e] + wsred[3][e] + (double)bg[e];
      if (v > best) { best = v; bi = e; }
    }
    const int pos = atomicAdd(&counts[bi], 1);
    rowlist[bi * B_ROWS + pos] = b;
  }
}

// ---------------- kernel B: grouped bf16-MFMA GEMM, 128x64 tiles ------------
// Occupancy play: 1536 real blocks, 24 KB LDS, acc 2x4 -> >=4 blocks/CU
// (16 waves/CU) plus two-generation phase skew. Work = (e, col, row-tile)
// with row-tile innermost: the 2 blocks sharing a W col-slice are dispatch-
// adjacent on the same XCD (bijective %8 swizzle) -> W read ~once via L2.
// Per-thread pipeline identical to the proven round-5 kernel.
__global__ __launch_bounds__(256, 4) void expert_gemm(
    const float* __restrict__ x, const float* __restrict__ W,
    const float* __restrict__ bias, const int* __restrict__ counts,
    const int* __restrict__ rowlist, float* __restrict__ out)
{
  const int bid = blockIdx.x;
  const int wk  = (bid & 7) * (NWORK / 8) + (bid >> 3);  // bijective [0,1536)
  const int e   = wk >> 7;               // 128 works per expert
  const int rem = wk & 127;
  const int c0  = (rem >> 1) * N_TILE;
  const int rt  = rem & 1;
  const int cnt  = counts[e];
  const int row0 = (blockIdx.y * 2 + rt) * M_TILE;
  if (row0 >= cnt) return;
  const int* rl  = rowlist + e * B_ROWS;

  __shared__ short8 xa[2][512];   // A: 2 x 8 KiB (128 rows x 32 k)
  __shared__ short8 wb[2][256];   // B: 2 x 4 KiB ( 64 cols x 32 k)

  const int tid  = threadIdx.x;
  const int lane = tid & 63;
  const int wave = tid >> 6;

  // staging geometry (fragment-order slots; all LDS ops wave-contiguous b128)
  const int sg  = (tid >> 4) & 3;   // k-subgroup (k = 8*sg + j)
  const int slr = tid & 15;         // lr / lc
  const int smb = tid >> 6;         // base frag-block

  // A: slots {tid, tid+256} -> rows 16*smb + slr, +64
  int arow0, arow1;
  {
    const int g0 = row0 + smb * 16 + slr;
    const int g1 = row0 + (smb + 4) * 16 + slr;
    arow0 = rl[g0 < cnt ? g0 : cnt - 1];
    arow1 = rl[g1 < cnt ? g1 : cnt - 1];
  }
  const float* xp0 = x + (size_t)arow0 * IN_DIM + sg * 8;
  const float* xp1 = x + (size_t)arow1 * IN_DIM + sg * 8;
  // B: slot tid -> col c0 + 16*smb + slr
  const float* wp  = W + (size_t)e * IN_DIM * OUT_DIM
                       + (size_t)(sg * 8) * OUT_DIM + c0 + smb * 16 + slr;

  // MFMA geometry: wave w -> rows [32w, 32w+32) x all 64 cols
  f32x4 acc[2][4];
  #pragma unroll
  for (int m = 0; m < 2; ++m)
    #pragma unroll
    for (int n = 0; n < 4; ++n)
      #pragma unroll
      for (int q = 0; q < 4; ++q) acc[m][n][q] = 0.f;

  float4 a0lo, a0hi, a1lo, a1hi;
  float w0[8];

#define ISSUE_LOADS(K)                                                  \
  {                                                                     \
    a0lo = *(const float4*)(xp0 + (K));                                 \
    a0hi = *(const float4*)(xp0 + (K) + 4);                             \
    a1lo = *(const float4*)(xp1 + (K));                                 \
    a1hi = *(const float4*)(xp1 + (K) + 4);                             \
    const float* p = wp + (size_t)(K) * OUT_DIM;                        \
    _Pragma("unroll")                                                   \
    for (int j = 0; j < 8; ++j) w0[j] = p[(size_t)j * OUT_DIM];         \
  }

  ISSUE_LOADS(0);

  for (int it = 0; it < NSTEP; ++it) {
    S8U av0, av1, bv0;
    av0.u[0] = cvt2(a0lo.x, a0lo.y); av0.u[1] = cvt2(a0lo.z, a0lo.w);
    av0.u[2] = cvt2(a0hi.x, a0hi.y); av0.u[3] = cvt2(a0hi.z, a0hi.w);
    av1.u[0] = cvt2(a1lo.x, a1lo.y); av1.u[1] = cvt2(a1lo.z, a1lo.w);
    av1.u[2] = cvt2(a1hi.x, a1hi.y); av1.u[3] = cvt2(a1hi.z, a1hi.w);
    #pragma unroll
    for (int q = 0; q < 4; ++q)
      bv0.u[q] = cvt2(w0[2 * q], w0[2 * q + 1]);

    if (it + 1 < NSTEP) ISSUE_LOADS((it + 1) * K_STEP);

    const int buf = it & 1;
    xa[buf][tid]       = av0.s;
    xa[buf][tid + 256] = av1.s;
    wb[buf][tid]       = bv0.s;
    barrier_lgkm();   // ds-writes visible; in-flight global loads survive

    short8 af[2], bf[4];
    #pragma unroll
    for (int m = 0; m < 2; ++m)
      af[m] = xa[buf][(2 * wave + m) * 64 + lane];
    #pragma unroll
    for (int n = 0; n < 4; ++n)
      bf[n] = wb[buf][n * 64 + lane];
    #pragma unroll
    for (int m = 0; m < 2; ++m)
      #pragma unroll
      for (int n = 0; n < 4; ++n)
        acc[m][n] = __builtin_amdgcn_mfma_f32_16x16x32_bf16(af[m], bf[n], acc[m][n], 0, 0, 0);
  }
#undef ISSUE_LOADS

  // epilogue: C/D layout col = lane&15, row = (lane>>4)*4 + r
  const int lr = lane & 15;
  const int lq = (lane >> 4) * 4;
  float bcol[4];
  #pragma unroll
  for (int n = 0; n < 4; ++n)
    bcol[n] = bias[e * OUT_DIM + c0 + n * 16 + lr];

  #pragma unroll
  for (int m = 0; m < 2; ++m) {
    #pragma unroll
    for (int r = 0; r < 4; ++r) {
      const int gidx = row0 + wave * 32 + m * 16 + lq + r;
      if (gidx >= cnt) continue;
      const int grow = rl[gidx];
      float* orow = out + (size_t)grow * OUT_DIM;
      #pragma unroll
      for (int n = 0; n < 4; ++n) {
        const int col = c0 + n * 16 + lr;
        orow[col] = acc[m][n][r] + bcol[n];
      }
    }
  }
}

extern "C" void kernel_launch(void* const* d_in, const int* in_sizes, int n_in,
                              void* d_out, int out_size, void* d_ws, size_t ws_size,
                              hipStream_t stream) {
  (void)in_sizes; (void)n_in; (void)out_size;
  const float* x  = (const float*)d_in[0];
  const float* t  = (const float*)d_in[1];
  const float* W  = (const float*)d_in[2];
  const float* bb = (const float*)d_in[3];
  const float* Wg = (const float*)d_in[4];
  const float* bg = (const float*)d_in[5];
  float* out = (float*)d_out;

  int*   counts  = (int*)d_ws;                                  // 16 ints
  int*   rowlist = (int*)d_ws + 16;                             // 12*2048 ints
  float* wgt     = (float*)((char*)d_ws + 64 + NE * B_ROWS * 4);// 12*4096 f32
  const size_t need = 64 + (size_t)NE * B_ROWS * 4 + (size_t)NE * OUT_DIM * 4;

  hipMemsetAsync(counts, 0, 16 * sizeof(int), stream);
  if (ws_size >= need) {
    wg_transpose<<<OUT_DIM / 256, 256, 0, stream>>>(Wg, wgt);
    gate_kernel<<<B_ROWS, 256, 0, stream>>>(t, wgt, bg, counts, rowlist);
  } else {
    gate_fallback<<<B_ROWS, 256, 0, stream>>>(t, Wg, bg, counts, rowlist);
  }

  // y covers row-tiles beyond 256 rows (early-exit; cnt>256 is ~7 sigma)
  dim3 grid(NWORK, (B_ROWS / M_TILE) / 2, 1);
  expert_gemm<<<grid, 256, 0, stream>>>(x, W, bb, counts, rowlist, out);
}

// Round 11
// 163.161 us; speedup vs baseline: 1.1618x; 1.1236x over previous
//
#include <hip/hip_runtime.h>
#include <hip/hip_bf16.h>

#define B_ROWS  2048
#define T_DIM   8
#define IN_DIM  1024
#define OUT_DIM 4096
#define NE      12

#define M_TILE 128
#define N_TILE 128
#define K_STEP 32
#define NSTEP  (IN_DIM / K_STEP)
#define PACK_TILES 2   // row-tiles (of 128) packed per expert = 256 rows

typedef __attribute__((ext_vector_type(8))) short short8;
typedef __attribute__((ext_vector_type(4))) float f32x4;

union S8U { short8 s; unsigned u[4]; };

// two floats -> packed bf16x2 (v_cvt_pk_bf16_f32, RNE)
__device__ __forceinline__ unsigned cvt2(float a, float b) {
  __hip_bfloat162 h = __float22bfloat162_rn(make_float2(a, b));
  union { __hip_bfloat162 h; unsigned u; } c; c.h = h;
  return c.u;
}

// barrier WITHOUT vmcnt drain (legacy kernel): ds-write visibility only
__device__ __forceinline__ void barrier_lgkm() {
  asm volatile("s_waitcnt lgkmcnt(0)" ::: "memory");
  __builtin_amdgcn_s_barrier();
}

// async global->LDS, 16B per lane: LDS dest = wave-uniform base + lane*16
__device__ __forceinline__ void gload_lds16(const void* g, void* l) {
  __builtin_amdgcn_global_load_lds(
      (const __attribute__((address_space(1))) void*)g,
      (__attribute__((address_space(3))) void*)l, 16, 0, 0);
}

// ---------------- kernel P: transpose Wg[4096][12] -> WgT[12][4096] --------
__global__ __launch_bounds__(256) void wg_transpose(
    const float* __restrict__ Wg, float* __restrict__ wgt)
{
  const int c = blockIdx.x * 256 + threadIdx.x;
  #pragma unroll
  for (int e = 0; e < NE; ++e)
    wgt[(size_t)e * OUT_DIM + c] = Wg[(size_t)c * NE + e];
}

// ---------------- kernel A: gate (round-5 passing version, unchanged) ------
__global__ __launch_bounds__(256) void gate_kernel(
    const float* __restrict__ t, const float* __restrict__ wgt,
    const float* __restrict__ bg, int* __restrict__ counts,
    int* __restrict__ rowlist)
{
  const int b   = blockIdx.x;
  const int tid = threadIdx.x;
  const float* tb = t + (size_t)b * T_DIM * OUT_DIM;

  float4 m[4];
  #pragma unroll
  for (int it = 0; it < 4; ++it) {
    const int c = (tid + it * 256) * 4;
    float4 s = make_float4(0.f, 0.f, 0.f, 0.f);
    #pragma unroll
    for (int tt = 0; tt < T_DIM; ++tt) {
      const float4 v = *(const float4*)(tb + (size_t)tt * OUT_DIM + c);
      s.x += v.x; s.y += v.y; s.z += v.z; s.w += v.w;
    }
    m[it] = make_float4(s.x * 0.125f, s.y * 0.125f, s.z * 0.125f, s.w * 0.125f);
  }

  float part[NE];
  #pragma unroll
  for (int e = 0; e < NE; ++e) {
    float acc = 0.f;
    #pragma unroll
    for (int it = 0; it < 4; ++it) {
      const int c = (tid + it * 256) * 4;
      const float4 w = *(const float4*)(wgt + (size_t)e * OUT_DIM + c);
      acc += m[it].x * w.x; acc += m[it].y * w.y;
      acc += m[it].z * w.z; acc += m[it].w * w.w;
    }
    part[e] = acc;
  }

  double d[NE];
  #pragma unroll
  for (int e = 0; e < NE; ++e) d[e] = (double)part[e];
  #pragma unroll
  for (int off = 32; off > 0; off >>= 1) {
    #pragma unroll
    for (int e = 0; e < NE; ++e) d[e] += __shfl_down(d[e], off, 64);
  }

  __shared__ double wsred[4][NE];
  const int lane = tid & 63, wave = tid >> 6;
  if (lane == 0) {
    #pragma unroll
    for (int e = 0; e < NE; ++e) wsred[wave][e] = d[e];
  }
  __syncthreads();

  if (tid == 0) {
    double best = -1e300; int bi = 0;
    #pragma unroll
    for (int e = 0; e < NE; ++e) {
      const double v = wsred[0][e] + wsred[1][e] + wsred[2][e] + wsred[3][e] + (double)bg[e];
      if (v > best) { best = v; bi = e; }
    }
    const int pos = atomicAdd(&counts[bi], 1);
    rowlist[bi * B_ROWS + pos] = b;
  }
}

// fallback gate (scalar Wg) if workspace can't hold WgT
__global__ __launch_bounds__(256) void gate_fallback(
    const float* __restrict__ t, const float* __restrict__ Wg,
    const float* __restrict__ bg, int* __restrict__ counts,
    int* __restrict__ rowlist)
{
  const int b   = blockIdx.x;
  const int tid = threadIdx.x;
  const float* tb = t + (size_t)b * T_DIM * OUT_DIM;

  float part[NE];
  #pragma unroll
  for (int e = 0; e < NE; ++e) part[e] = 0.f;
  #pragma unroll
  for (int it = 0; it < 4; ++it) {
    const int c = (tid + it * 256) * 4;
    float4 s = make_float4(0.f, 0.f, 0.f, 0.f);
    #pragma unroll
    for (int tt = 0; tt < T_DIM; ++tt) {
      const float4 v = *(const float4*)(tb + (size_t)tt * OUT_DIM + c);
      s.x += v.x; s.y += v.y; s.z += v.z; s.w += v.w;
    }
    const float mm[4] = { s.x * 0.125f, s.y * 0.125f, s.z * 0.125f, s.w * 0.125f };
    #pragma unroll
    for (int j = 0; j < 4; ++j) {
      const float* wg = Wg + (size_t)(c + j) * NE;
      #pragma unroll
      for (int e = 0; e < NE; ++e) part[e] += mm[j] * wg[e];
    }
  }
  double d[NE];
  #pragma unroll
  for (int e = 0; e < NE; ++e) d[e] = (double)part[e];
  #pragma unroll
  for (int off = 32; off > 0; off >>= 1) {
    #pragma unroll
    for (int e = 0; e < NE; ++e) d[e] += __shfl_down(d[e], off, 64);
  }
  __shared__ double wsred[4][NE];
  const int lane = tid & 63, wave = tid >> 6;
  if (lane == 0) {
    #pragma unroll
    for (int e = 0; e < NE; ++e) wsred[wave][e] = d[e];
  }
  __syncthreads();
  if (tid == 0) {
    double best = -1e300; int bi = 0;
    #pragma unroll
    for (int e = 0; e < NE; ++e) {
      const double v = wsred[0][e] + wsred[1][e] + wsred[2][e] + wsred[3][e] + (double)bg[e];
      if (v > best) { best = v; bi = e; }
    }
    const int pos = atomicAdd(&counts[bi], 1);
    rowlist[bi * B_ROWS + pos] = b;
  }
}

// ---------------- kernel X: pack gathered x into bf16 fragment-slot order --
// pxa[(e*2+rt)][k-step][slot], slot semantics identical to the GEMM's LDS:
// slot s holds bf16 x[rl[rt*128 + 16*(s>>6) + (s&15)]][k0 + 8*((s>>4)&3) + j].
// The gather (16 scattered rows per wave-instruction) is paid ONCE here
// instead of once per col-block (32x) in the GEMM.
__global__ __launch_bounds__(256) void pack_x(
    const float* __restrict__ x, const int* __restrict__ counts,
    const int* __restrict__ rowlist, short8* __restrict__ pxa)
{
  const int e   = blockIdx.x;
  const int rt  = blockIdx.y;
  const int it  = blockIdx.z;     // k-step
  const int cnt = counts[e];
  const int row0 = rt * M_TILE;
  if (row0 >= cnt) return;
  const int* rl = rowlist + e * B_ROWS;
  const int tid = threadIdx.x;
  const int sg = (tid >> 4) & 3, slr = tid & 15, smb = tid >> 6;

  int g0 = row0 + smb * 16 + slr;        g0 = g0 < cnt ? g0 : cnt - 1;
  int g1 = row0 + (smb + 4) * 16 + slr;  g1 = g1 < cnt ? g1 : cnt - 1;
  const float* xp0 = x + (size_t)rl[g0] * IN_DIM + sg * 8 + it * K_STEP;
  const float* xp1 = x + (size_t)rl[g1] * IN_DIM + sg * 8 + it * K_STEP;

  const float4 a = *(const float4*)xp0, b = *(const float4*)(xp0 + 4);
  const float4 c = *(const float4*)xp1, d = *(const float4*)(xp1 + 4);
  S8U v0, v1;
  v0.u[0] = cvt2(a.x, a.y); v0.u[1] = cvt2(a.z, a.w);
  v0.u[2] = cvt2(b.x, b.y); v0.u[3] = cvt2(b.z, b.w);
  v1.u[0] = cvt2(c.x, c.y); v1.u[1] = cvt2(c.z, c.w);
  v1.u[2] = cvt2(d.x, d.y); v1.u[3] = cvt2(d.z, d.w);

  short8* dst = pxa + ((size_t)(e * PACK_TILES + rt) * NSTEP + it) * 512;
  dst[tid]       = v0.s;   // dense wave-contiguous 16B stores
  dst[tid + 256] = v1.s;
}

// ---------------- kernel B1: GEMM, packed-A via global_load_lds -------------
// A-side: 2 dense global_load_lds dwordx4 per thread per step (1 KB/wave-op,
// direct to LDS, no VGPR roundtrip, no convert). W-side: r5 path unchanged.
// Counted barrier: vmcnt(16) keeps next step's 16 W loads in flight while
// draining this step's 2 A-gloads; sched_barrier(0) pins issue order so the
// count is exact.
__global__ __launch_bounds__(256) void expert_gemm_packed(
    const float* __restrict__ W, const float* __restrict__ bias,
    const int* __restrict__ counts, const int* __restrict__ rowlist,
    const short8* __restrict__ pxa, float* __restrict__ out)
{
  const int e    = blockIdx.z;
  const int cnt  = counts[e];
  const int row0 = blockIdx.y * M_TILE;   // y in [0, PACK_TILES)
  if (row0 >= cnt) return;
  const int c0   = blockIdx.x * N_TILE;
  const int* rl  = rowlist + e * B_ROWS;

  __shared__ short8 xa[2][512];
  __shared__ short8 wb[2][512];

  const int tid  = threadIdx.x;
  const int lane = tid & 63;
  const int wave = tid >> 6;
  const int sg = (tid >> 4) & 3, slr = tid & 15, smb = tid >> 6;

  const float* wp = W + (size_t)e * IN_DIM * OUT_DIM
                      + (size_t)(sg * 8) * OUT_DIM + c0 + smb * 16 + slr;

  // per-lane packed-A source (slot = wave*128 + lane, +64); + it*512 per step
  const short8* at = pxa + (size_t)(e * PACK_TILES + blockIdx.y) * NSTEP * 512
                   + wave * 128 + lane;

  const int wm = (wave >> 1) * 64, wn = (wave & 1) * 64;
  const int abase = (wave >> 1) * 256, bbase = (wave & 1) * 256;

  f32x4 acc[4][4];
  #pragma unroll
  for (int m = 0; m < 4; ++m)
    #pragma unroll
    for (int n = 0; n < 4; ++n)
      #pragma unroll
      for (int q = 0; q < 4; ++q) acc[m][n][q] = 0.f;

  float w0[8], w1[8];

#define W_ISSUE(K)                                                      \
  {                                                                     \
    const float* p = wp + (size_t)(K) * OUT_DIM;                        \
    _Pragma("unroll")                                                   \
    for (int j = 0; j < 8; ++j) {                                       \
      w0[j] = p[(size_t)j * OUT_DIM];                                   \
      w1[j] = p[(size_t)j * OUT_DIM + 64];                              \
    }                                                                   \
  }

  // prologue: W(0) first (older), then A(0) (younger) — matches steady state
  W_ISSUE(0);
  gload_lds16(at,      &xa[0][wave * 128]);
  gload_lds16(at + 64, &xa[0][wave * 128 + 64]);
  __builtin_amdgcn_sched_barrier(0);

  #pragma unroll 2
  for (int it = 0; it < NSTEP; ++it) {
    const int buf = it & 1;

    // convert W(it) (dep-wait drains W(it); A(it) is younger, stays in flight)
    S8U bv0, bv1;
    #pragma unroll
    for (int q = 0; q < 4; ++q) {
      bv0.u[q] = cvt2(w0[2 * q], w0[2 * q + 1]);
      bv1.u[q] = cvt2(w1[2 * q], w1[2 * q + 1]);
    }

    // issue W(it+1) (wrapped on last iter so vmcnt count stays exact)
    const int itn = (it + 1 < NSTEP) ? it + 1 : 0;
    W_ISSUE(itn * K_STEP);

    wb[buf][tid]       = bv0.s;
    wb[buf][tid + 256] = bv1.s;

    // drain A(it) (2 oldest) + ds_writes; keep W(it+1) (16 youngest) in flight
    asm volatile("s_waitcnt vmcnt(16) lgkmcnt(0)" ::: "memory");
    __builtin_amdgcn_s_barrier();

    // issue A(it+1) into the other buffer (safe: all reads of it done)
    gload_lds16(at + (size_t)itn * 512,      &xa[buf ^ 1][wave * 128]);
    gload_lds16(at + (size_t)itn * 512 + 64, &xa[buf ^ 1][wave * 128 + 64]);
    __builtin_amdgcn_sched_barrier(0);

    short8 af[4], bf[4];
    #pragma unroll
    for (int m = 0; m < 4; ++m) af[m] = xa[buf][abase + m * 64 + lane];
    #pragma unroll
    for (int n = 0; n < 4; ++n) bf[n] = wb[buf][bbase + n * 64 + lane];
    #pragma unroll
    for (int m = 0; m < 4; ++m)
      #pragma unroll
      for (int n = 0; n < 4; ++n)
        acc[m][n] = __builtin_amdgcn_mfma_f32_16x16x32_bf16(af[m], bf[n], acc[m][n], 0, 0, 0);
  }
#undef W_ISSUE

  // epilogue: C/D layout col = lane&15, row = (lane>>4)*4 + r
  const int lr = lane & 15;
  const int lq = (lane >> 4) * 4;
  float bcol[4];
  #pragma unroll
  for (int n = 0; n < 4; ++n)
    bcol[n] = bias[e * OUT_DIM + c0 + wn + n * 16 + lr];

  #pragma unroll
  for (int m = 0; m < 4; ++m) {
    #pragma unroll
    for (int r = 0; r < 4; ++r) {
      const int gidx = row0 + wm + m * 16 + lq + r;
      if (gidx >= cnt) continue;
      const int grow = rl[gidx];
      float* orow = out + (size_t)grow * OUT_DIM;
      #pragma unroll
      for (int n = 0; n < 4; ++n) {
        const int col = c0 + wn + n * 16 + lr;
        orow[col] = acc[m][n][r] + bcol[n];
      }
    }
  }
}

// ---------------- kernel B2: legacy r5 GEMM (fallback + cnt>256 catcher) ----
__global__ __launch_bounds__(256) void expert_gemm_legacy(
    const float* __restrict__ x, const float* __restrict__ W,
    const float* __restrict__ bias, const int* __restrict__ counts,
    const int* __restrict__ rowlist, float* __restrict__ out, int y_off)
{
  const int e    = blockIdx.z;
  const int cnt  = counts[e];
  const int row0 = (blockIdx.y + y_off) * M_TILE;
  if (row0 >= cnt) return;
  const int c0   = blockIdx.x * N_TILE;
  const int* rl  = rowlist + e * B_ROWS;

  __shared__ short8 xa[2][512];
  __shared__ short8 wb[2][512];

  const int tid  = threadIdx.x;
  const int lane = tid & 63;
  const int wave = tid >> 6;
  const int sg  = (tid >> 4) & 3;
  const int slr = tid & 15;
  const int smb = tid >> 6;

  int arow0, arow1;
  {
    const int g0 = row0 + smb * 16 + slr;
    const int g1 = row0 + (smb + 4) * 16 + slr;
    arow0 = rl[g0 < cnt ? g0 : cnt - 1];
    arow1 = rl[g1 < cnt ? g1 : cnt - 1];
  }
  const float* xp0 = x + (size_t)arow0 * IN_DIM + sg * 8;
  const float* xp1 = x + (size_t)arow1 * IN_DIM + sg * 8;
  const float* wp  = W + (size_t)e * IN_DIM * OUT_DIM
                       + (size_t)(sg * 8) * OUT_DIM + c0 + smb * 16 + slr;

  const int wm = (wave >> 1) * 64;
  const int wn = (wave & 1) * 64;
  const int abase = (wave >> 1) * 256;
  const int bbase = (wave & 1) * 256;

  f32x4 acc[4][4];
  #pragma unroll
  for (int m = 0; m < 4; ++m)
    #pragma unroll
    for (int n = 0; n < 4; ++n)
      #pragma unroll
      for (int q = 0; q < 4; ++q) acc[m][n][q] = 0.f;

  float4 a0lo, a0hi, a1lo, a1hi;
  float w0[8], w1[8];

#define ISSUE_LOADS(K)                                                  \
  {                                                                     \
    a0lo = *(const float4*)(xp0 + (K));                                 \
    a0hi = *(const float4*)(xp0 + (K) + 4);                             \
    a1lo = *(const float4*)(xp1 + (K));                                 \
    a1hi = *(const float4*)(xp1 + (K) + 4);                             \
    const float* p = wp + (size_t)(K) * OUT_DIM;                        \
    _Pragma("unroll")                                                   \
    for (int j = 0; j < 8; ++j) {                                       \
      w0[j] = p[(size_t)j * OUT_DIM];                                   \
      w1[j] = p[(size_t)j * OUT_DIM + 64];                              \
    }                                                                   \
  }

  ISSUE_LOADS(0);

  for (int it = 0; it < NSTEP; ++it) {
    S8U av0, av1, bv0, bv1;
    av0.u[0] = cvt2(a0lo.x, a0lo.y); av0.u[1] = cvt2(a0lo.z, a0lo.w);
    av0.u[2] = cvt2(a0hi.x, a0hi.y); av0.u[3] = cvt2(a0hi.z, a0hi.w);
    av1.u[0] = cvt2(a1lo.x, a1lo.y); av1.u[1] = cvt2(a1lo.z, a1lo.w);
    av1.u[2] = cvt2(a1hi.x, a1hi.y); av1.u[3] = cvt2(a1hi.z, a1hi.w);
    #pragma unroll
    for (int q = 0; q < 4; ++q) {
      bv0.u[q] = cvt2(w0[2 * q], w0[2 * q + 1]);
      bv1.u[q] = cvt2(w1[2 * q], w1[2 * q + 1]);
    }

    if (it + 1 < NSTEP) ISSUE_LOADS((it + 1) * K_STEP);

    const int buf = it & 1;
    xa[buf][tid]       = av0.s;
    xa[buf][tid + 256] = av1.s;
    wb[buf][tid]       = bv0.s;
    wb[buf][tid + 256] = bv1.s;
    barrier_lgkm();

    short8 af[4], bf[4];
    #pragma unroll
    for (int m = 0; m < 4; ++m) af[m] = xa[buf][abase + m * 64 + lane];
    #pragma unroll
    for (int n = 0; n < 4; ++n) bf[n] = wb[buf][bbase + n * 64 + lane];
    #pragma unroll
    for (int m = 0; m < 4; ++m)
      #pragma unroll
      for (int n = 0; n < 4; ++n)
        acc[m][n] = __builtin_amdgcn_mfma_f32_16x16x32_bf16(af[m], bf[n], acc[m][n], 0, 0, 0);
  }
#undef ISSUE_LOADS

  const int lr = lane & 15;
  const int lq = (lane >> 4) * 4;
  float bcol[4];
  #pragma unroll
  for (int n = 0; n < 4; ++n)
    bcol[n] = bias[e * OUT_DIM + c0 + wn + n * 16 + lr];

  #pragma unroll
  for (int m = 0; m < 4; ++m) {
    #pragma unroll
    for (int r = 0; r < 4; ++r) {
      const int gidx = row0 + wm + m * 16 + lq + r;
      if (gidx >= cnt) continue;
      const int grow = rl[gidx];
      float* orow = out + (size_t)grow * OUT_DIM;
      #pragma unroll
      for (int n = 0; n < 4; ++n) {
        const int col = c0 + wn + n * 16 + lr;
        orow[col] = acc[m][n][r] + bcol[n];
      }
    }
  }
}

extern "C" void kernel_launch(void* const* d_in, const int* in_sizes, int n_in,
                              void* d_out, int out_size, void* d_ws, size_t ws_size,
                              hipStream_t stream) {
  (void)in_sizes; (void)n_in; (void)out_size;
  const float* x  = (const float*)d_in[0];
  const float* t  = (const float*)d_in[1];
  const float* W  = (const float*)d_in[2];
  const float* bb = (const float*)d_in[3];
  const float* Wg = (const float*)d_in[4];
  const float* bg = (const float*)d_in[5];
  float* out = (float*)d_out;

  char*  base    = (char*)d_ws;
  int*   counts  = (int*)base;                       // 64 B
  int*   rowlist = (int*)(base + 64);                // 12*2048*4 = 98304 B
  float* wgt     = (float*)(base + 98368);           // 12*4096*4 = 196608 B
  short8* pxa    = (short8*)(base + 295936);         // 12*2*32*512*16 = 6 MB
  const size_t need_wgt  = 98368 + 196608;           // 294976
  const size_t need_pack = 295936 + (size_t)NE * PACK_TILES * NSTEP * 512 * 16;

  hipMemsetAsync(counts, 0, 64, stream);
  if (ws_size >= need_wgt) {
    wg_transpose<<<OUT_DIM / 256, 256, 0, stream>>>(Wg, wgt);
    gate_kernel<<<B_ROWS, 256, 0, stream>>>(t, wgt, bg, counts, rowlist);
  } else {
    gate_fallback<<<B_ROWS, 256, 0, stream>>>(t, Wg, bg, counts, rowlist);
  }

  if (ws_size >= need_pack) {
    pack_x<<<dim3(NE, PACK_TILES, NSTEP), 256, 0, stream>>>(x, counts, rowlist, pxa);
    expert_gemm_packed<<<dim3(OUT_DIM / N_TILE, PACK_TILES, NE), 256, 0, stream>>>(
        W, bb, counts, rowlist, pxa, out);
    // catcher for the (statistically impossible) cnt > 256 case
    expert_gemm_legacy<<<dim3(OUT_DIM / N_TILE, B_ROWS / M_TILE - PACK_TILES, NE),
                         256, 0, stream>>>(x, W, bb, counts, rowlist, out, PACK_TILES);
  } else {
    expert_gemm_legacy<<<dim3(OUT_DIM / N_TILE, B_ROWS / M_TILE, NE),
                         256, 0, stream>>>(x, W, bb, counts, rowlist, out, 0);
  }
}